// Round 1
// baseline (43.330 us; speedup 1.0000x reference)
//
#include <hip/hip_runtime.h>
#include <math.h>

#define NN 8192
#define ROWS_PER_BLOCK 4

__global__ __launch_bounds__(256, 2)
void lif_r_kernel(const float* __restrict__ x_in,
                  const float* __restrict__ v,
                  const float* __restrict__ g,
                  const float* __restrict__ theta_s,
                  const float* __restrict__ w,
                  const float* __restrict__ E_L,
                  const float* __restrict__ C_m,
                  const float* __restrict__ Gc,
                  const float* __restrict__ tau_g,
                  float* __restrict__ out)
{
    const int wave = threadIdx.x >> 6;      // 0..3
    const int lane = threadIdx.x & 63;
    const int row  = blockIdx.x * ROWS_PER_BLOCK + wave;

    const float4* __restrict__ wrow =
        reinterpret_cast<const float4*>(w + (size_t)row * NN);
    const float4* __restrict__ g4 = reinterpret_cast<const float4*>(g);

    // Each lane: 32 float4 loads, stride 64 float4s (1 KiB) per step.
    float acc = 0.0f;
#pragma unroll
    for (int k = 0; k < NN / 4 / 64; ++k) {
        const int idx = lane + 64 * k;
        const float4 wv = wrow[idx];
        const float4 gv = g4[idx];
        acc += wv.x * gv.x + wv.y * gv.y + wv.z * gv.z + wv.w * gv.w;
    }

    // 64-lane tree reduction
#pragma unroll
    for (int off = 32; off > 0; off >>= 1)
        acc += __shfl_down(acc, off, 64);

    if (lane == 0) {
        const float I      = acc + x_in[row];
        const float vv     = v[row];
        const float el     = E_L[row];
        const float th     = theta_s[row];
        const float dv     = (Gc[row] * (el - vv) + I * 18.0f) / C_m[row];
        const float v_next = vv + dv;
        const float d      = v_next - th;
        const float spk_soft = 1.0f / (1.0f + expf(-d));
        const float spiked   = (v_next >= th) ? 1.0f : 0.0f;
        const float v_reset  = el + 0.12f * (vv - el) - 12.0f;
        const float v_new    = spiked * v_reset + (1.0f - spiked) * v_next;
        out[row]      = v_new;     // output 0: v_new
        out[NN + row] = spk_soft;  // output 1: spiked_soft
        (void)tau_g;               // g/theta hidden-state updates are discarded
    }
}

extern "C" void kernel_launch(void* const* d_in, const int* in_sizes, int n_in,
                              void* d_out, int out_size, void* d_ws, size_t ws_size,
                              hipStream_t stream)
{
    const float* x_in    = (const float*)d_in[0];
    const float* v       = (const float*)d_in[1];
    const float* g       = (const float*)d_in[2];
    const float* theta_s = (const float*)d_in[3];
    const float* w       = (const float*)d_in[4];
    const float* E_L     = (const float*)d_in[5];
    const float* C_m     = (const float*)d_in[6];
    const float* Gc      = (const float*)d_in[7];
    const float* tau_g   = (const float*)d_in[8];
    float* out = (float*)d_out;

    dim3 grid(NN / ROWS_PER_BLOCK);   // 2048 blocks
    dim3 block(256);
    lif_r_kernel<<<grid, block, 0, stream>>>(x_in, v, g, theta_s, w,
                                             E_L, C_m, Gc, tau_g, out);
}